// Round 15
// baseline (77.567 us; speedup 1.0000x reference)
//
#include <hip/hip_runtime.h>
#include <hip/hip_bf16.h>
#include <math.h>

#define NN 8192
#define FF 256
#define ALPHA 0.2f
#define CAP 512   // per-row edge cap; nnz ~ Binomial(8192,0.01): mean 82, sd 9 -> 48 sigma
#define GEMM_BLOCKS 256   // NN/32

typedef float f32x4 __attribute__((ext_vector_type(4)));
typedef float f32x2 __attribute__((ext_vector_type(2)));
typedef short bf16x8 __attribute__((ext_vector_type(8)));

static __device__ __forceinline__ unsigned short f2bf(float f) {
  __hip_bfloat16 h = __float2bfloat16(f);
  return *reinterpret_cast<unsigned short*>(&h);
}

// convert 8 consecutive fp32 (16B-aligned) to a bf16x8 MFMA fragment
static __device__ __forceinline__ bf16x8 cvt8(const float* __restrict__ p) {
  f32x4 v0 = *reinterpret_cast<const f32x4*>(p);
  f32x4 v1 = *reinterpret_cast<const f32x4*>(p + 4);
  bf16x8 r;
  r[0] = (short)f2bf(v0[0]); r[1] = (short)f2bf(v0[1]);
  r[2] = (short)f2bf(v0[2]); r[3] = (short)f2bf(v0[3]);
  r[4] = (short)f2bf(v1[0]); r[5] = (short)f2bf(v1[1]);
  r[6] = (short)f2bf(v1[2]); r[7] = (short)f2bf(v1[3]);
  return r;
}

// ---------------------------------------------------------------------------
// FUSED kernel (identical to R10/R14): blocks [0,256) = MFMA gemm;
// blocks [256,2304) = adj stream with plain cached loads.
// ---------------------------------------------------------------------------
__global__ __launch_bounds__(256) void fused_gemm_stream_kernel(
    const float* __restrict__ x, const float* __restrict__ W,
    const float* __restrict__ asrc, const float* __restrict__ adst,
    float* __restrict__ a_src, float* __restrict__ a_dst,
    unsigned short* __restrict__ h_bf,
    const float* __restrict__ adj, int* __restrict__ cnt_g,
    unsigned* __restrict__ idx_g) {
  __shared__ float s_red[2][2][2][16];  // gemm path only (512 B)
  const int t = threadIdx.x;
  const int lane = t & 63, w = t >> 6;

  if (blockIdx.x < GEMM_BLOCKS) {
    const int rg = w >> 1;
    const int nh = w & 1;
    const int i0 = blockIdx.x * 32;
    const int l16 = lane & 15;
    const int kq  = lane >> 4;

    const float* xrow = x + (size_t)(i0 + rg * 16 + l16) * FF + kq * 8;
    const float* wrow = W + (size_t)(nh * 128 + l16) * FF + kq * 8;

    f32x4 acc[8];
#pragma unroll
    for (int n = 0; n < 8; ++n) acc[n] = (f32x4){0.f, 0.f, 0.f, 0.f};

#pragma unroll
    for (int k8 = 0; k8 < 8; ++k8) {
      bf16x8 a = cvt8(xrow + k8 * 32);
#pragma unroll
      for (int n = 0; n < 8; ++n) {
        bf16x8 b = cvt8(wrow + (size_t)n * 16 * FF + k8 * 32);
        acc[n] = __builtin_amdgcn_mfma_f32_16x16x32_bf16(a, b, acc[n], 0, 0, 0);
      }
    }

    float ps[4] = {0.f, 0.f, 0.f, 0.f};
    float pd[4] = {0.f, 0.f, 0.f, 0.f};
#pragma unroll
    for (int n = 0; n < 8; ++n) {
      const int c = nh * 128 + n * 16 + l16;
      const float as_c = asrc[c];
      const float ad_c = adst[c];
#pragma unroll
      for (int r = 0; r < 4; ++r) {
        float v = acc[n][r];
        int row = i0 + rg * 16 + kq * 4 + r;
        h_bf[(size_t)row * FF + c] = f2bf(v);
        ps[r] = fmaf(v, as_c, ps[r]);
        pd[r] = fmaf(v, ad_c, pd[r]);
      }
    }
#pragma unroll
    for (int r = 0; r < 4; ++r) {
#pragma unroll
      for (int d = 1; d < 16; d <<= 1) {
        ps[r] += __shfl_xor(ps[r], d, 64);
        pd[r] += __shfl_xor(pd[r], d, 64);
      }
    }
    if (l16 == 0) {
#pragma unroll
      for (int r = 0; r < 4; ++r) {
        s_red[0][rg][nh][kq * 4 + r] = ps[r];
        s_red[1][rg][nh][kq * 4 + r] = pd[r];
      }
    }
    __syncthreads();
    if (t < 32) {
      int rr = t & 15, g = t >> 4;
      a_src[i0 + g * 16 + rr] = s_red[0][g][0][rr] + s_red[0][g][1][rr];
      a_dst[i0 + g * 16 + rr] = s_red[1][g][0][rr] + s_red[1][g][1][rr];
    }
  } else {
    const int i = (blockIdx.x - GEMM_BLOCKS) * 4 + w;
    const f32x4* adj4 = reinterpret_cast<const f32x4*>(adj + (size_t)i * NN);
    unsigned* rowidx = idx_g + (size_t)i * CAP;

    int cnt = 0;
#pragma unroll
    for (int half = 0; half < 2; ++half) {
      f32x4 v[16];
#pragma unroll
      for (int q = 0; q < 16; ++q)
        v[q] = adj4[half * 1024 + q * 64 + lane];
      unsigned long long m = 0ull;
#pragma unroll
      for (int q = 0; q < 16; ++q) {
#pragma unroll
        for (int u = 0; u < 4; ++u)
          m |= (v[q][u] > 0.f ? 1ull : 0ull) << (q * 4 + u);
      }
      int c_t = __popcll(m);
      int scan = c_t;
#pragma unroll
      for (int d = 1; d < 64; d <<= 1) {
        int nv = __shfl_up(scan, d, 64);
        if (lane >= d) scan += nv;
      }
      int tot = __shfl(scan, 63, 64);
      int off = cnt + scan - c_t;
      while (m) {
        int b = __builtin_ctzll(m);
        m &= m - 1ull;
        if (off < CAP)
          rowidx[off] = (unsigned)(half * 4096 + ((b >> 2) << 8) + (lane << 2) + (b & 3));
        ++off;
      }
      cnt += tot;
    }
    if (lane == 0) cnt_g[i] = cnt > CAP ? CAP : cnt;
  }
}

// ---------------------------------------------------------------------------
// Kernel 2: softmax + aggregation. Half-wave uint4 gather (R14) + packed
// f32x2 FMA (v_pk_fma_f32) + 8-pair-deep load pipeline.
// ---------------------------------------------------------------------------
__global__ __launch_bounds__(256) void attn_kernel(
    const int* __restrict__ cnt_g, const unsigned* __restrict__ idx_g,
    const float* __restrict__ a_src, const float* __restrict__ a_dst,
    const unsigned short* __restrict__ h_bf, float* __restrict__ out) {
  __shared__ __align__(16) uint2 s_edge[4][CAP + 2];   // +pad slot per wave
  const int t = threadIdx.x;
  const int lane = t & 63, w = t >> 6;
  const int half = lane >> 5, l32 = lane & 31;
  const int i = blockIdx.x * 4 + w;
  uint2* edge = s_edge[w];

  const float a_d = a_dst[i];
  const int cnt = cnt_g[i];
  const unsigned* rowidx = idx_g + (size_t)i * CAP;

  // scores + max (ref row-max includes exact 0.0 of masked-out entries)
  float lmax = 0.f;
  for (int p = lane; p < cnt; p += 64) {
    int j = (int)rowidx[p];
    float s = a_src[j] + a_d;
    float lk = s > 0.f ? s : ALPHA * s;
    edge[p].x = (unsigned)j;
    edge[p].y = __float_as_uint(lk);
    lmax = fmaxf(lmax, lk);
  }
  if (lane == 0) { edge[cnt].x = 0u; edge[cnt].y = 0u; }  // zero-weight pad
#pragma unroll
  for (int d = 32; d; d >>= 1) lmax = fmaxf(lmax, __shfl_xor(lmax, d, 64));

  // exp + sum
  float lsum = 0.f;
  for (int p = lane; p < cnt; p += 64) {
    float e = __expf(__uint_as_float(edge[p].y) - lmax);
    edge[p].y = __float_as_uint(e);
    lsum += e;
  }
#pragma unroll
  for (int d = 32; d; d >>= 1) lsum += __shfl_xor(lsum, d, 64);
  const float inv = 1.f / (lsum + 1e-8f);

  // gather: lane handles 8 channels (uint4) of edge (2pp+half).
  // acc kept as 4 x f32x2 so each uint's two bf16 channels become one
  // v_pk_fma_f32. Per-channel fma order identical to scalar -> bit-identical.
  const uint4* h4 = reinterpret_cast<const uint4*>(h_bf);  // 32 uint4 per row
  f32x2 acc2[4];
#pragma unroll
  for (int k = 0; k < 4; ++k) acc2[k] = (f32x2){0.f, 0.f};

#define ACC8P(g, wv)                                                         \
  acc2[0] = __builtin_elementwise_fma(                                       \
      wv, (f32x2){__uint_as_float((g).x << 16),                              \
                  __uint_as_float((g).x & 0xffff0000u)}, acc2[0]);           \
  acc2[1] = __builtin_elementwise_fma(                                       \
      wv, (f32x2){__uint_as_float((g).y << 16),                              \
                  __uint_as_float((g).y & 0xffff0000u)}, acc2[1]);           \
  acc2[2] = __builtin_elementwise_fma(                                       \
      wv, (f32x2){__uint_as_float((g).z << 16),                              \
                  __uint_as_float((g).z & 0xffff0000u)}, acc2[2]);           \
  acc2[3] = __builtin_elementwise_fma(                                       \
      wv, (f32x2){__uint_as_float((g).w << 16),                              \
                  __uint_as_float((g).w & 0xffff0000u)}, acc2[3]);

  const int npairs = (cnt + 1) >> 1;
  int pp = 0;
  for (; pp + 8 <= npairs; pp += 8) {
    uint2 e[8];
    uint4 g[8];
#pragma unroll
    for (int q = 0; q < 8; ++q) e[q] = edge[(pp + q) * 2 + half];
#pragma unroll
    for (int q = 0; q < 8; ++q) g[q] = h4[(size_t)e[q].x * 32 + l32];
#pragma unroll
    for (int q = 0; q < 8; ++q) {
      float wq = __uint_as_float(e[q].y);
      f32x2 wv = (f32x2){wq, wq};
      ACC8P(g[q], wv);
    }
  }
  for (; pp < npairs; ++pp) {
    uint2 e0 = edge[pp * 2 + half];
    uint4 g0 = h4[(size_t)e0.x * 32 + l32];
    float w0 = __uint_as_float(e0.y);
    f32x2 wv = (f32x2){w0, w0};
    ACC8P(g0, wv);
  }
#undef ACC8P

  // combine halves: each channel's partial lives in lane and lane^32
  float acc[8];
#pragma unroll
  for (int k = 0; k < 4; ++k) { acc[2 * k] = acc2[k][0]; acc[2 * k + 1] = acc2[k][1]; }
#pragma unroll
  for (int k = 0; k < 8; ++k) acc[k] += __shfl_xor(acc[k], 32, 64);

  // epilogue: half h writes channels l32*8 + half*4 .. +3 (acc[half*4+u])
  const int b4 = half * 4;
  f32x4 o4;
#pragma unroll
  for (int u = 0; u < 4; ++u) {
    float v = acc[b4 + u] * inv;
    o4[u] = v > 0.f ? v : (__expf(v) - 1.f);
  }
  reinterpret_cast<f32x4*>(out)[(size_t)i * 64 + l32 * 2 + half] = o4;
}

// ---------------------------------------------------------------------------
extern "C" void kernel_launch(void* const* d_in, const int* in_sizes, int n_in,
                              void* d_out, int out_size, void* d_ws, size_t ws_size,
                              hipStream_t stream) {
  const float* x        = (const float*)d_in[0];   // (8192,256)
  const float* adj      = (const float*)d_in[1];   // (8192,8192)
  const float* W        = (const float*)d_in[2];   // (256,256)
  const float* attn_src = (const float*)d_in[3];   // (1,256)
  const float* attn_dst = (const float*)d_in[4];   // (1,256)
  float* out = (float*)d_out;                      // (8192,256) fp32

  // ws: a_src 32K | a_dst 32K | h_bf 4M | cnt 32K | idx 16M
  char* ws = (char*)d_ws;
  float* a_src = (float*)ws;
  float* a_dst = (float*)(ws + 32768);
  unsigned short* h_bf = (unsigned short*)(ws + 65536);
  int* cnt_g = (int*)(ws + 65536 + 4194304);
  unsigned* idx_g = (unsigned*)(ws + 65536 + 4194304 + 32768);

  hipLaunchKernelGGL(fused_gemm_stream_kernel,
                     dim3(GEMM_BLOCKS + NN / 4), dim3(256), 0, stream,
                     x, W, attn_src, attn_dst, a_src, a_dst, h_bf,
                     adj, cnt_g, idx_g);
  hipLaunchKernelGGL(attn_kernel, dim3(NN / 4), dim3(256), 0, stream,
                     cnt_g, idx_g, a_src, a_dst, h_bf, out);
}

// Round 16
// 74.963 us; speedup vs baseline: 1.0347x; 1.0347x over previous
//
#include <hip/hip_runtime.h>
#include <hip/hip_bf16.h>
#include <math.h>

#define NN 8192
#define FF 256
#define ALPHA 0.2f
#define CAP 512   // per-row edge cap; nnz ~ Binomial(8192,0.01): mean 82, sd 9 -> 48 sigma
#define GEMM_BLOCKS 256   // NN/32

typedef float f32x4 __attribute__((ext_vector_type(4)));
typedef short bf16x8 __attribute__((ext_vector_type(8)));

static __device__ __forceinline__ unsigned short f2bf(float f) {
  __hip_bfloat16 h = __float2bfloat16(f);
  return *reinterpret_cast<unsigned short*>(&h);
}

// convert 8 consecutive fp32 (16B-aligned) to a bf16x8 MFMA fragment
static __device__ __forceinline__ bf16x8 cvt8(const float* __restrict__ p) {
  f32x4 v0 = *reinterpret_cast<const f32x4*>(p);
  f32x4 v1 = *reinterpret_cast<const f32x4*>(p + 4);
  bf16x8 r;
  r[0] = (short)f2bf(v0[0]); r[1] = (short)f2bf(v0[1]);
  r[2] = (short)f2bf(v0[2]); r[3] = (short)f2bf(v0[3]);
  r[4] = (short)f2bf(v1[0]); r[5] = (short)f2bf(v1[1]);
  r[6] = (short)f2bf(v1[2]); r[7] = (short)f2bf(v1[3]);
  return r;
}

// ---------------------------------------------------------------------------
// FUSED kernel (identical to R10/R14): blocks [0,256) = MFMA gemm;
// blocks [256,2304) = adj stream with plain cached loads.
// ---------------------------------------------------------------------------
__global__ __launch_bounds__(256) void fused_gemm_stream_kernel(
    const float* __restrict__ x, const float* __restrict__ W,
    const float* __restrict__ asrc, const float* __restrict__ adst,
    float* __restrict__ a_src, float* __restrict__ a_dst,
    unsigned short* __restrict__ h_bf,
    const float* __restrict__ adj, int* __restrict__ cnt_g,
    unsigned* __restrict__ idx_g) {
  __shared__ float s_red[2][2][2][16];  // gemm path only (512 B)
  const int t = threadIdx.x;
  const int lane = t & 63, w = t >> 6;

  if (blockIdx.x < GEMM_BLOCKS) {
    const int rg = w >> 1;
    const int nh = w & 1;
    const int i0 = blockIdx.x * 32;
    const int l16 = lane & 15;
    const int kq  = lane >> 4;

    const float* xrow = x + (size_t)(i0 + rg * 16 + l16) * FF + kq * 8;
    const float* wrow = W + (size_t)(nh * 128 + l16) * FF + kq * 8;

    f32x4 acc[8];
#pragma unroll
    for (int n = 0; n < 8; ++n) acc[n] = (f32x4){0.f, 0.f, 0.f, 0.f};

#pragma unroll
    for (int k8 = 0; k8 < 8; ++k8) {
      bf16x8 a = cvt8(xrow + k8 * 32);
#pragma unroll
      for (int n = 0; n < 8; ++n) {
        bf16x8 b = cvt8(wrow + (size_t)n * 16 * FF + k8 * 32);
        acc[n] = __builtin_amdgcn_mfma_f32_16x16x32_bf16(a, b, acc[n], 0, 0, 0);
      }
    }

    float ps[4] = {0.f, 0.f, 0.f, 0.f};
    float pd[4] = {0.f, 0.f, 0.f, 0.f};
#pragma unroll
    for (int n = 0; n < 8; ++n) {
      const int c = nh * 128 + n * 16 + l16;
      const float as_c = asrc[c];
      const float ad_c = adst[c];
#pragma unroll
      for (int r = 0; r < 4; ++r) {
        float v = acc[n][r];
        int row = i0 + rg * 16 + kq * 4 + r;
        h_bf[(size_t)row * FF + c] = f2bf(v);
        ps[r] = fmaf(v, as_c, ps[r]);
        pd[r] = fmaf(v, ad_c, pd[r]);
      }
    }
#pragma unroll
    for (int r = 0; r < 4; ++r) {
#pragma unroll
      for (int d = 1; d < 16; d <<= 1) {
        ps[r] += __shfl_xor(ps[r], d, 64);
        pd[r] += __shfl_xor(pd[r], d, 64);
      }
    }
    if (l16 == 0) {
#pragma unroll
      for (int r = 0; r < 4; ++r) {
        s_red[0][rg][nh][kq * 4 + r] = ps[r];
        s_red[1][rg][nh][kq * 4 + r] = pd[r];
      }
    }
    __syncthreads();
    if (t < 32) {
      int rr = t & 15, g = t >> 4;
      a_src[i0 + g * 16 + rr] = s_red[0][g][0][rr] + s_red[0][g][1][rr];
      a_dst[i0 + g * 16 + rr] = s_red[1][g][0][rr] + s_red[1][g][1][rr];
    }
  } else {
    const int i = (blockIdx.x - GEMM_BLOCKS) * 4 + w;
    const f32x4* adj4 = reinterpret_cast<const f32x4*>(adj + (size_t)i * NN);
    unsigned* rowidx = idx_g + (size_t)i * CAP;

    int cnt = 0;
#pragma unroll
    for (int half = 0; half < 2; ++half) {
      f32x4 v[16];
#pragma unroll
      for (int q = 0; q < 16; ++q)
        v[q] = adj4[half * 1024 + q * 64 + lane];
      unsigned long long m = 0ull;
#pragma unroll
      for (int q = 0; q < 16; ++q) {
#pragma unroll
        for (int u = 0; u < 4; ++u)
          m |= (v[q][u] > 0.f ? 1ull : 0ull) << (q * 4 + u);
      }
      int c_t = __popcll(m);
      int scan = c_t;
#pragma unroll
      for (int d = 1; d < 64; d <<= 1) {
        int nv = __shfl_up(scan, d, 64);
        if (lane >= d) scan += nv;
      }
      int tot = __shfl(scan, 63, 64);
      int off = cnt + scan - c_t;
      while (m) {
        int b = __builtin_ctzll(m);
        m &= m - 1ull;
        if (off < CAP)
          rowidx[off] = (unsigned)(half * 4096 + ((b >> 2) << 8) + (lane << 2) + (b & 3));
        ++off;
      }
      cnt += tot;
    }
    if (lane == 0) cnt_g[i] = cnt > CAP ? CAP : cnt;
  }
}

// ---------------------------------------------------------------------------
// Kernel 2: softmax + aggregation. R14's half-wave uint4 gather (proven) +
// register-resident scores for cnt<=128 (all rows in practice; LDS fallback
// for correctness). Saves one LDS write+read pass per row.
// ---------------------------------------------------------------------------
__global__ __launch_bounds__(256) void attn_kernel(
    const int* __restrict__ cnt_g, const unsigned* __restrict__ idx_g,
    const float* __restrict__ a_src, const float* __restrict__ a_dst,
    const unsigned short* __restrict__ h_bf, float* __restrict__ out) {
  __shared__ __align__(16) uint2 s_edge[4][CAP + 2];   // +pad slot per wave
  const int t = threadIdx.x;
  const int lane = t & 63, w = t >> 6;
  const int half = lane >> 5, l32 = lane & 31;
  const int i = blockIdx.x * 4 + w;
  uint2* edge = s_edge[w];

  const float a_d = a_dst[i];
  const int cnt = cnt_g[i];
  const unsigned* rowidx = idx_g + (size_t)i * CAP;

  // ---- scores + max + exp + sum ----
  // ref row-max includes the exact 0.0 of masked-out entries -> init 0.
  float lmax = 0.f, lsum = 0.f;
  if (cnt <= 128) {
    // fast path: scores live in registers (<=2 per lane)
    const int p0 = lane, p1 = lane + 64;
    float s0 = 0.f, s1 = 0.f;
    if (p0 < cnt) {
      int j = (int)rowidx[p0];
      float s = a_src[j] + a_d;
      s0 = s > 0.f ? s : ALPHA * s;
      edge[p0].x = (unsigned)j;
      lmax = fmaxf(lmax, s0);
    }
    if (p1 < cnt) {
      int j = (int)rowidx[p1];
      float s = a_src[j] + a_d;
      s1 = s > 0.f ? s : ALPHA * s;
      edge[p1].x = (unsigned)j;
      lmax = fmaxf(lmax, s1);
    }
#pragma unroll
    for (int d = 32; d; d >>= 1) lmax = fmaxf(lmax, __shfl_xor(lmax, d, 64));
    if (p0 < cnt) {
      float e = __expf(s0 - lmax);
      edge[p0].y = __float_as_uint(e);
      lsum += e;
    }
    if (p1 < cnt) {
      float e = __expf(s1 - lmax);
      edge[p1].y = __float_as_uint(e);
      lsum += e;
    }
#pragma unroll
    for (int d = 32; d; d >>= 1) lsum += __shfl_xor(lsum, d, 64);
  } else {
    // fallback (cnt>128 ~ never): LDS round-trip as in R14
    for (int p = lane; p < cnt; p += 64) {
      int j = (int)rowidx[p];
      float s = a_src[j] + a_d;
      float lk = s > 0.f ? s : ALPHA * s;
      edge[p].x = (unsigned)j;
      edge[p].y = __float_as_uint(lk);
      lmax = fmaxf(lmax, lk);
    }
#pragma unroll
    for (int d = 32; d; d >>= 1) lmax = fmaxf(lmax, __shfl_xor(lmax, d, 64));
    for (int p = lane; p < cnt; p += 64) {
      float e = __expf(__uint_as_float(edge[p].y) - lmax);
      edge[p].y = __float_as_uint(e);
      lsum += e;
    }
#pragma unroll
    for (int d = 32; d; d >>= 1) lsum += __shfl_xor(lsum, d, 64);
  }
  if (lane == 0) { edge[cnt].x = 0u; edge[cnt].y = 0u; }  // zero-weight pad
  const float inv = 1.f / (lsum + 1e-8f);

  // ---- gather (R14 verbatim): half-wave uint4, 4-pair unroll ----
  const uint4* h4 = reinterpret_cast<const uint4*>(h_bf);  // 32 uint4 per row
  float acc[8];
#pragma unroll
  for (int k = 0; k < 8; ++k) acc[k] = 0.f;

#define ACC8(g, wt)                                               \
  acc[0] = fmaf(wt, __uint_as_float((g).x << 16), acc[0]);        \
  acc[1] = fmaf(wt, __uint_as_float((g).x & 0xffff0000u), acc[1]);\
  acc[2] = fmaf(wt, __uint_as_float((g).y << 16), acc[2]);        \
  acc[3] = fmaf(wt, __uint_as_float((g).y & 0xffff0000u), acc[3]);\
  acc[4] = fmaf(wt, __uint_as_float((g).z << 16), acc[4]);        \
  acc[5] = fmaf(wt, __uint_as_float((g).z & 0xffff0000u), acc[5]);\
  acc[6] = fmaf(wt, __uint_as_float((g).w << 16), acc[6]);        \
  acc[7] = fmaf(wt, __uint_as_float((g).w & 0xffff0000u), acc[7]);

  const int npairs = (cnt + 1) >> 1;
  int pp = 0;
  for (; pp + 4 <= npairs; pp += 4) {
    uint2 e0 = edge[pp * 2 + half];
    uint2 e1 = edge[pp * 2 + 2 + half];
    uint2 e2 = edge[pp * 2 + 4 + half];
    uint2 e3 = edge[pp * 2 + 6 + half];
    uint4 g0 = h4[(size_t)e0.x * 32 + l32];
    uint4 g1 = h4[(size_t)e1.x * 32 + l32];
    uint4 g2 = h4[(size_t)e2.x * 32 + l32];
    uint4 g3 = h4[(size_t)e3.x * 32 + l32];
    float w0 = __uint_as_float(e0.y), w1 = __uint_as_float(e1.y);
    float w2 = __uint_as_float(e2.y), w3 = __uint_as_float(e3.y);
    ACC8(g0, w0); ACC8(g1, w1); ACC8(g2, w2); ACC8(g3, w3);
  }
  for (; pp < npairs; ++pp) {
    uint2 e0 = edge[pp * 2 + half];
    uint4 g0 = h4[(size_t)e0.x * 32 + l32];
    float w0 = __uint_as_float(e0.y);
    ACC8(g0, w0);
  }
#undef ACC8

  // combine halves: each channel's partial lives in lane and lane^32
#pragma unroll
  for (int k = 0; k < 8; ++k) acc[k] += __shfl_xor(acc[k], 32, 64);

  // epilogue: half h writes channels l32*8 + half*4 .. +3 (acc[half*4+u])
  const int b4 = half * 4;
  f32x4 o4;
#pragma unroll
  for (int u = 0; u < 4; ++u) {
    float v = acc[b4 + u] * inv;
    o4[u] = v > 0.f ? v : (__expf(v) - 1.f);
  }
  reinterpret_cast<f32x4*>(out)[(size_t)i * 64 + l32 * 2 + half] = o4;
}

// ---------------------------------------------------------------------------
extern "C" void kernel_launch(void* const* d_in, const int* in_sizes, int n_in,
                              void* d_out, int out_size, void* d_ws, size_t ws_size,
                              hipStream_t stream) {
  const float* x        = (const float*)d_in[0];   // (8192,256)
  const float* adj      = (const float*)d_in[1];   // (8192,8192)
  const float* W        = (const float*)d_in[2];   // (256,256)
  const float* attn_src = (const float*)d_in[3];   // (1,256)
  const float* attn_dst = (const float*)d_in[4];   // (1,256)
  float* out = (float*)d_out;                      // (8192,256) fp32

  // ws: a_src 32K | a_dst 32K | h_bf 4M | cnt 32K | idx 16M
  char* ws = (char*)d_ws;
  float* a_src = (float*)ws;
  float* a_dst = (float*)(ws + 32768);
  unsigned short* h_bf = (unsigned short*)(ws + 65536);
  int* cnt_g = (int*)(ws + 65536 + 4194304);
  unsigned* idx_g = (unsigned*)(ws + 65536 + 4194304 + 32768);

  hipLaunchKernelGGL(fused_gemm_stream_kernel,
                     dim3(GEMM_BLOCKS + NN / 4), dim3(256), 0, stream,
                     x, W, attn_src, attn_dst, a_src, a_dst, h_bf,
                     adj, cnt_g, idx_g);
  hipLaunchKernelGGL(attn_kernel, dim3(NN / 4), dim3(256), 0, stream,
                     cnt_g, idx_g, a_src, a_dst, h_bf, out);
}

// Round 17
// 74.898 us; speedup vs baseline: 1.0356x; 1.0009x over previous
//
#include <hip/hip_runtime.h>
#include <hip/hip_bf16.h>
#include <math.h>

#define NN 8192
#define FF 256
#define ALPHA 0.2f
#define CAP 512   // per-row edge cap; nnz ~ Binomial(8192,0.01): mean 82, sd 9 -> 48 sigma
#define GEMM_BLOCKS 256   // NN/32

typedef float f32x4 __attribute__((ext_vector_type(4)));
typedef float f32x2 __attribute__((ext_vector_type(2)));
typedef short bf16x8 __attribute__((ext_vector_type(8)));

static __device__ __forceinline__ unsigned short f2bf(float f) {
  __hip_bfloat16 h = __float2bfloat16(f);
  return *reinterpret_cast<unsigned short*>(&h);
}

// convert 8 consecutive fp32 (16B-aligned) to a bf16x8 MFMA fragment
static __device__ __forceinline__ bf16x8 cvt8(const float* __restrict__ p) {
  f32x4 v0 = *reinterpret_cast<const f32x4*>(p);
  f32x4 v1 = *reinterpret_cast<const f32x4*>(p + 4);
  bf16x8 r;
  r[0] = (short)f2bf(v0[0]); r[1] = (short)f2bf(v0[1]);
  r[2] = (short)f2bf(v0[2]); r[3] = (short)f2bf(v0[3]);
  r[4] = (short)f2bf(v1[0]); r[5] = (short)f2bf(v1[1]);
  r[6] = (short)f2bf(v1[2]); r[7] = (short)f2bf(v1[3]);
  return r;
}

// ---------------------------------------------------------------------------
// FUSED kernel (identical to R10/R14/R16): blocks [0,256) = MFMA gemm;
// blocks [256,2304) = adj stream with plain cached loads.
// ---------------------------------------------------------------------------
__global__ __launch_bounds__(256) void fused_gemm_stream_kernel(
    const float* __restrict__ x, const float* __restrict__ W,
    const float* __restrict__ asrc, const float* __restrict__ adst,
    float* __restrict__ a_src, float* __restrict__ a_dst,
    unsigned short* __restrict__ h_bf,
    const float* __restrict__ adj, int* __restrict__ cnt_g,
    unsigned* __restrict__ idx_g) {
  __shared__ float s_red[2][2][2][16];  // gemm path only (512 B)
  const int t = threadIdx.x;
  const int lane = t & 63, w = t >> 6;

  if (blockIdx.x < GEMM_BLOCKS) {
    const int rg = w >> 1;
    const int nh = w & 1;
    const int i0 = blockIdx.x * 32;
    const int l16 = lane & 15;
    const int kq  = lane >> 4;

    const float* xrow = x + (size_t)(i0 + rg * 16 + l16) * FF + kq * 8;
    const float* wrow = W + (size_t)(nh * 128 + l16) * FF + kq * 8;

    f32x4 acc[8];
#pragma unroll
    for (int n = 0; n < 8; ++n) acc[n] = (f32x4){0.f, 0.f, 0.f, 0.f};

#pragma unroll
    for (int k8 = 0; k8 < 8; ++k8) {
      bf16x8 a = cvt8(xrow + k8 * 32);
#pragma unroll
      for (int n = 0; n < 8; ++n) {
        bf16x8 b = cvt8(wrow + (size_t)n * 16 * FF + k8 * 32);
        acc[n] = __builtin_amdgcn_mfma_f32_16x16x32_bf16(a, b, acc[n], 0, 0, 0);
      }
    }

    float ps[4] = {0.f, 0.f, 0.f, 0.f};
    float pd[4] = {0.f, 0.f, 0.f, 0.f};
#pragma unroll
    for (int n = 0; n < 8; ++n) {
      const int c = nh * 128 + n * 16 + l16;
      const float as_c = asrc[c];
      const float ad_c = adst[c];
#pragma unroll
      for (int r = 0; r < 4; ++r) {
        float v = acc[n][r];
        int row = i0 + rg * 16 + kq * 4 + r;
        h_bf[(size_t)row * FF + c] = f2bf(v);
        ps[r] = fmaf(v, as_c, ps[r]);
        pd[r] = fmaf(v, ad_c, pd[r]);
      }
    }
#pragma unroll
    for (int r = 0; r < 4; ++r) {
#pragma unroll
      for (int d = 1; d < 16; d <<= 1) {
        ps[r] += __shfl_xor(ps[r], d, 64);
        pd[r] += __shfl_xor(pd[r], d, 64);
      }
    }
    if (l16 == 0) {
#pragma unroll
      for (int r = 0; r < 4; ++r) {
        s_red[0][rg][nh][kq * 4 + r] = ps[r];
        s_red[1][rg][nh][kq * 4 + r] = pd[r];
      }
    }
    __syncthreads();
    if (t < 32) {
      int rr = t & 15, g = t >> 4;
      a_src[i0 + g * 16 + rr] = s_red[0][g][0][rr] + s_red[0][g][1][rr];
      a_dst[i0 + g * 16 + rr] = s_red[1][g][0][rr] + s_red[1][g][1][rr];
    }
  } else {
    const int i = (blockIdx.x - GEMM_BLOCKS) * 4 + w;
    const f32x4* adj4 = reinterpret_cast<const f32x4*>(adj + (size_t)i * NN);
    unsigned* rowidx = idx_g + (size_t)i * CAP;

    int cnt = 0;
#pragma unroll
    for (int half = 0; half < 2; ++half) {
      f32x4 v[16];
#pragma unroll
      for (int q = 0; q < 16; ++q)
        v[q] = adj4[half * 1024 + q * 64 + lane];
      unsigned long long m = 0ull;
#pragma unroll
      for (int q = 0; q < 16; ++q) {
#pragma unroll
        for (int u = 0; u < 4; ++u)
          m |= (v[q][u] > 0.f ? 1ull : 0ull) << (q * 4 + u);
      }
      int c_t = __popcll(m);
      int scan = c_t;
#pragma unroll
      for (int d = 1; d < 64; d <<= 1) {
        int nv = __shfl_up(scan, d, 64);
        if (lane >= d) scan += nv;
      }
      int tot = __shfl(scan, 63, 64);
      int off = cnt + scan - c_t;
      while (m) {
        int b = __builtin_ctzll(m);
        m &= m - 1ull;
        if (off < CAP)
          rowidx[off] = (unsigned)(half * 4096 + ((b >> 2) << 8) + (lane << 2) + (b & 3));
        ++off;
      }
      cnt += tot;
    }
    if (lane == 0) cnt_g[i] = cnt > CAP ? CAP : cnt;
  }
}

// ---------------------------------------------------------------------------
// Kernel 2: softmax + aggregation. R16 base; ONLY change: accumulate with
// inline-asm v_pk_fma_f32 (VOP3P, D = S0*S1 + S2) -> per uint4 the 8 FMA
// become 4 packed FMA. Per-channel math/rounding identical to scalar fmaf.
// ---------------------------------------------------------------------------
__global__ __launch_bounds__(256) void attn_kernel(
    const int* __restrict__ cnt_g, const unsigned* __restrict__ idx_g,
    const float* __restrict__ a_src, const float* __restrict__ a_dst,
    const unsigned short* __restrict__ h_bf, float* __restrict__ out) {
  __shared__ __align__(16) uint2 s_edge[4][CAP + 2];   // +pad slot per wave
  const int t = threadIdx.x;
  const int lane = t & 63, w = t >> 6;
  const int half = lane >> 5, l32 = lane & 31;
  const int i = blockIdx.x * 4 + w;
  uint2* edge = s_edge[w];

  const float a_d = a_dst[i];
  const int cnt = cnt_g[i];
  const unsigned* rowidx = idx_g + (size_t)i * CAP;

  // ---- scores + max + exp + sum (R16: register-resident for cnt<=128) ----
  float lmax = 0.f, lsum = 0.f;
  if (cnt <= 128) {
    const int p0 = lane, p1 = lane + 64;
    float s0 = 0.f, s1 = 0.f;
    if (p0 < cnt) {
      int j = (int)rowidx[p0];
      float s = a_src[j] + a_d;
      s0 = s > 0.f ? s : ALPHA * s;
      edge[p0].x = (unsigned)j;
      lmax = fmaxf(lmax, s0);
    }
    if (p1 < cnt) {
      int j = (int)rowidx[p1];
      float s = a_src[j] + a_d;
      s1 = s > 0.f ? s : ALPHA * s;
      edge[p1].x = (unsigned)j;
      lmax = fmaxf(lmax, s1);
    }
#pragma unroll
    for (int d = 32; d; d >>= 1) lmax = fmaxf(lmax, __shfl_xor(lmax, d, 64));
    if (p0 < cnt) {
      float e = __expf(s0 - lmax);
      edge[p0].y = __float_as_uint(e);
      lsum += e;
    }
    if (p1 < cnt) {
      float e = __expf(s1 - lmax);
      edge[p1].y = __float_as_uint(e);
      lsum += e;
    }
#pragma unroll
    for (int d = 32; d; d >>= 1) lsum += __shfl_xor(lsum, d, 64);
  } else {
    for (int p = lane; p < cnt; p += 64) {
      int j = (int)rowidx[p];
      float s = a_src[j] + a_d;
      float lk = s > 0.f ? s : ALPHA * s;
      edge[p].x = (unsigned)j;
      edge[p].y = __float_as_uint(lk);
      lmax = fmaxf(lmax, lk);
    }
#pragma unroll
    for (int d = 32; d; d >>= 1) lmax = fmaxf(lmax, __shfl_xor(lmax, d, 64));
    for (int p = lane; p < cnt; p += 64) {
      float e = __expf(__uint_as_float(edge[p].y) - lmax);
      edge[p].y = __float_as_uint(e);
      lsum += e;
    }
#pragma unroll
    for (int d = 32; d; d >>= 1) lsum += __shfl_xor(lsum, d, 64);
  }
  if (lane == 0) { edge[cnt].x = 0u; edge[cnt].y = 0u; }  // zero-weight pad
  const float inv = 1.f / (lsum + 1e-8f);

  // ---- gather: half-wave uint4, 4-pair unroll (R14 structure) ----
  const uint4* h4 = reinterpret_cast<const uint4*>(h_bf);  // 32 uint4 per row
  f32x2 acc2[4];
#pragma unroll
  for (int k = 0; k < 4; ++k) acc2[k] = (f32x2){0.f, 0.f};

  // acc2[k] += wv * {lo,hi} via one v_pk_fma_f32 per uint
#define PKFMA(accv, wv, uval)                                                \
  {                                                                          \
    f32x2 hv_ = {__uint_as_float((uval) << 16),                              \
                 __uint_as_float((uval) & 0xffff0000u)};                     \
    asm("v_pk_fma_f32 %0, %1, %2, %0" : "+v"(accv) : "v"(wv), "v"(hv_));     \
  }
#define ACC8PK(g, wv)     \
  PKFMA(acc2[0], wv, (g).x) \
  PKFMA(acc2[1], wv, (g).y) \
  PKFMA(acc2[2], wv, (g).z) \
  PKFMA(acc2[3], wv, (g).w)

  const int npairs = (cnt + 1) >> 1;
  int pp = 0;
  for (; pp + 4 <= npairs; pp += 4) {
    uint2 e0 = edge[pp * 2 + half];
    uint2 e1 = edge[pp * 2 + 2 + half];
    uint2 e2 = edge[pp * 2 + 4 + half];
    uint2 e3 = edge[pp * 2 + 6 + half];
    uint4 g0 = h4[(size_t)e0.x * 32 + l32];
    uint4 g1 = h4[(size_t)e1.x * 32 + l32];
    uint4 g2 = h4[(size_t)e2.x * 32 + l32];
    uint4 g3 = h4[(size_t)e3.x * 32 + l32];
    f32x2 w0 = {__uint_as_float(e0.y), __uint_as_float(e0.y)};
    f32x2 w1 = {__uint_as_float(e1.y), __uint_as_float(e1.y)};
    f32x2 w2 = {__uint_as_float(e2.y), __uint_as_float(e2.y)};
    f32x2 w3 = {__uint_as_float(e3.y), __uint_as_float(e3.y)};
    ACC8PK(g0, w0); ACC8PK(g1, w1); ACC8PK(g2, w2); ACC8PK(g3, w3);
  }
  for (; pp < npairs; ++pp) {
    uint2 e0 = edge[pp * 2 + half];
    uint4 g0 = h4[(size_t)e0.x * 32 + l32];
    f32x2 w0 = {__uint_as_float(e0.y), __uint_as_float(e0.y)};
    ACC8PK(g0, w0);
  }
#undef ACC8PK
#undef PKFMA

  // combine halves: each channel's partial lives in lane and lane^32
  float acc[8];
#pragma unroll
  for (int k = 0; k < 4; ++k) { acc[2 * k] = acc2[k][0]; acc[2 * k + 1] = acc2[k][1]; }
#pragma unroll
  for (int k = 0; k < 8; ++k) acc[k] += __shfl_xor(acc[k], 32, 64);

  // epilogue: half h writes channels l32*8 + half*4 .. +3 (acc[half*4+u])
  const int b4 = half * 4;
  f32x4 o4;
#pragma unroll
  for (int u = 0; u < 4; ++u) {
    float v = acc[b4 + u] * inv;
    o4[u] = v > 0.f ? v : (__expf(v) - 1.f);
  }
  reinterpret_cast<f32x4*>(out)[(size_t)i * 64 + l32 * 2 + half] = o4;
}

// ---------------------------------------------------------------------------
extern "C" void kernel_launch(void* const* d_in, const int* in_sizes, int n_in,
                              void* d_out, int out_size, void* d_ws, size_t ws_size,
                              hipStream_t stream) {
  const float* x        = (const float*)d_in[0];   // (8192,256)
  const float* adj      = (const float*)d_in[1];   // (8192,8192)
  const float* W        = (const float*)d_in[2];   // (256,256)
  const float* attn_src = (const float*)d_in[3];   // (1,256)
  const float* attn_dst = (const float*)d_in[4];   // (1,256)
  float* out = (float*)d_out;                      // (8192,256) fp32

  // ws: a_src 32K | a_dst 32K | h_bf 4M | cnt 32K | idx 16M
  char* ws = (char*)d_ws;
  float* a_src = (float*)ws;
  float* a_dst = (float*)(ws + 32768);
  unsigned short* h_bf = (unsigned short*)(ws + 65536);
  int* cnt_g = (int*)(ws + 65536 + 4194304);
  unsigned* idx_g = (unsigned*)(ws + 65536 + 4194304 + 32768);

  hipLaunchKernelGGL(fused_gemm_stream_kernel,
                     dim3(GEMM_BLOCKS + NN / 4), dim3(256), 0, stream,
                     x, W, attn_src, attn_dst, a_src, a_dst, h_bf,
                     adj, cnt_g, idx_g);
  hipLaunchKernelGGL(attn_kernel, dim3(NN / 4), dim3(256), 0, stream,
                     cnt_g, idx_g, a_src, a_dst, h_bf, out);
}